// Round 1
// baseline (1058.043 us; speedup 1.0000x reference)
//
#include <hip/hip_runtime.h>

#define N_NODES 40000
#define N_EDGES 640000
#define DIM 128
#define N_GRAPHS 64
#define BN_EPS 1e-5f
#define AGG_BLOCKS 1024

// ---------------- CSR build ----------------
__global__ __launch_bounds__(256) void k_count_edges(const int* __restrict__ ei, int* __restrict__ cnt) {
    int e = blockIdx.x * 256 + threadIdx.x;
    if (e < N_EDGES) atomicAdd(&cnt[ei[N_EDGES + e]], 1);   // dst row
}

__global__ __launch_bounds__(256) void k_count_nodes(const int* __restrict__ batch, int* __restrict__ gcnt) {
    int n = blockIdx.x * 256 + threadIdx.x;
    if (n < N_NODES) atomicAdd(&gcnt[batch[n]], 1);
}

__global__ __launch_bounds__(1024) void k_scan(const int* __restrict__ cnt, int* __restrict__ off,
                                               int* __restrict__ pos, float* __restrict__ dinv,
                                               const int* __restrict__ gcnt, int* __restrict__ goff) {
    __shared__ int sums[1024];
    int t = threadIdx.x;
    const int CH = (N_NODES + 1023) / 1024;           // 40
    int b0 = t * CH;
    int b1 = b0 + CH; if (b1 > N_NODES) b1 = N_NODES;
    if (b0 > N_NODES) b0 = N_NODES;
    int s = 0;
    for (int i = b0; i < b1; ++i) s += cnt[i];
    sums[t] = s;
    __syncthreads();
    for (int d = 1; d < 1024; d <<= 1) {
        int v = (t >= d) ? sums[t - d] : 0;
        __syncthreads();
        sums[t] += v;
        __syncthreads();
    }
    int run = sums[t] - s;                            // exclusive prefix
    for (int i = b0; i < b1; ++i) {
        off[i] = run; pos[i] = run;
        dinv[i] = rsqrtf((float)(cnt[i] + 1));        // +1 self loop, always > 0
        run += cnt[i];
    }
    if (b1 == N_NODES && b0 < N_NODES) off[N_NODES] = run;
    if (t == 0) {
        int r = 0;
        for (int g = 0; g < N_GRAPHS; ++g) { goff[g] = r; r += gcnt[g]; }
        goff[N_GRAPHS] = r;
    }
}

__global__ __launch_bounds__(256) void k_fill(const int* __restrict__ ei, int* __restrict__ pos,
                                              int* __restrict__ elist, float* __restrict__ coef,
                                              const float* __restrict__ dinv) {
    int e = blockIdx.x * 256 + threadIdx.x;
    if (e < N_EDGES) {
        int s = ei[e];                 // src row
        int d = ei[N_EDGES + e];       // dst row
        int p = atomicAdd(&pos[d], 1);
        elist[p] = s;
        coef[p]  = dinv[s] * dinv[d];
    }
}

// ---------------- GEMM: out = affine(in) @ W + b ----------------
// 64 rows per block, 256 threads; W (128x128) + in-tile staged in LDS.
__global__ __launch_bounds__(256) void k_gemm(const float* __restrict__ in, const float* __restrict__ W,
                                              const float* __restrict__ bias, const float* __restrict__ ac,
                                              float* __restrict__ out) {
    __shared__ float Wl[DIM * DIM];        // 64 KB
    __shared__ float inl[64 * 132];        // padded stride (conflict-free reads)
    int t = threadIdx.x;
    long row0 = (long)blockIdx.x * 64;

    const float4* W4 = (const float4*)W;
    float4* Wl4 = (float4*)Wl;
#pragma unroll
    for (int i = 0; i < 16; ++i) Wl4[t + i * 256] = W4[t + i * 256];

    for (int i = t; i < 2048; i += 256) {      // 64 rows x 32 float4
        int r = i >> 5, k4 = i & 31;
        float4 v = ((const float4*)(in + (row0 + r) * DIM))[k4];
        if (ac) {
            int k = k4 * 4;
            v.x = fmaf(ac[k + 0], v.x, ac[DIM + k + 0]);
            v.y = fmaf(ac[k + 1], v.y, ac[DIM + k + 1]);
            v.z = fmaf(ac[k + 2], v.z, ac[DIM + k + 2]);
            v.w = fmaf(ac[k + 3], v.w, ac[DIM + k + 3]);
        }
        *(float4*)&inl[r * 132 + k4 * 4] = v;
    }
    __syncthreads();

    int ty = t >> 4, tx = t & 15;
    int r0 = ty * 4, c0 = tx * 4;              // cols c0..c0+3 and 64+c0..64+c0+3
    float acc[4][8];
#pragma unroll
    for (int i = 0; i < 4; ++i)
#pragma unroll
        for (int j = 0; j < 8; ++j) acc[i][j] = 0.f;

#pragma unroll 4
    for (int k = 0; k < DIM; ++k) {
        float av[4];
#pragma unroll
        for (int i = 0; i < 4; ++i) av[i] = inl[(r0 + i) * 132 + k];
        float4 wA = *(const float4*)&Wl[k * DIM + c0];
        float4 wB = *(const float4*)&Wl[k * DIM + 64 + c0];
        float wv[8] = {wA.x, wA.y, wA.z, wA.w, wB.x, wB.y, wB.z, wB.w};
#pragma unroll
        for (int i = 0; i < 4; ++i)
#pragma unroll
            for (int j = 0; j < 8; ++j)
                acc[i][j] = fmaf(av[i], wv[j], acc[i][j]);
    }

    float4 bA = *(const float4*)&bias[c0];
    float4 bB = *(const float4*)&bias[64 + c0];
#pragma unroll
    for (int i = 0; i < 4; ++i) {
        long r = row0 + r0 + i;
        float4 oA = make_float4(acc[i][0] + bA.x, acc[i][1] + bA.y, acc[i][2] + bA.z, acc[i][3] + bA.w);
        float4 oB = make_float4(acc[i][4] + bB.x, acc[i][5] + bB.y, acc[i][6] + bB.z, acc[i][7] + bB.w);
        *(float4*)&out[r * DIM + c0] = oA;
        *(float4*)&out[r * DIM + 64 + c0] = oB;
    }
}

// ---------------- Aggregation + ReLU + BN partial stats ----------------
// one wave per dst node (grid-stride); lane handles cols lane, lane+64.
__global__ __launch_bounds__(256) void k_agg(const float* __restrict__ hW, const int* __restrict__ off,
                                             const int* __restrict__ elist, const float* __restrict__ coef,
                                             const float* __restrict__ dinv, float* __restrict__ hout,
                                             float* __restrict__ partials) {
    __shared__ float colacc[256];
    colacc[threadIdx.x] = 0.f;
    __syncthreads();

    int lane = threadIdx.x & 63;
    int wid = (blockIdx.x * 256 + threadIdx.x) >> 6;
    const int NW = AGG_BLOCKS * 4;
    float s0 = 0.f, s1 = 0.f, q0 = 0.f, q1 = 0.f;

    for (int i = wid; i < N_NODES; i += NW) {
        float di = dinv[i];
        const float* rowi = hW + (long)i * DIM;
        float selfc = di * di;
        float a0 = rowi[lane] * selfc;
        float a1 = rowi[lane + 64] * selfc;
        int e  = off[i];
        int e1 = off[i + 1];
#pragma unroll 2
        for (; e < e1; ++e) {
            int s  = elist[e];
            float c = coef[e];
            const float* rs = hW + (long)s * DIM;
            a0 = fmaf(rs[lane], c, a0);
            a1 = fmaf(rs[lane + 64], c, a1);
        }
        a0 = fmaxf(a0, 0.f);
        a1 = fmaxf(a1, 0.f);
        hout[(long)i * DIM + lane]      = a0;
        hout[(long)i * DIM + lane + 64] = a1;
        s0 += a0; s1 += a1; q0 += a0 * a0; q1 += a1 * a1;
    }

    atomicAdd(&colacc[lane], s0);
    atomicAdd(&colacc[lane + 64], s1);
    atomicAdd(&colacc[lane + 128], q0);
    atomicAdd(&colacc[lane + 192], q1);
    __syncthreads();
    partials[(long)blockIdx.x * 256 + threadIdx.x] = colacc[threadIdx.x];
}

// ---------------- BN stats -> affine a,c ----------------
__global__ __launch_bounds__(512) void k_stats(const float* __restrict__ partials,
                                               const float* __restrict__ gamma, const float* __restrict__ beta,
                                               float* __restrict__ ac) {
    __shared__ float ls[512], lq[512];
    int d = threadIdx.x & 127;
    int seg = threadIdx.x >> 7;
    float s = 0.f, q = 0.f;
    for (int b = seg; b < AGG_BLOCKS; b += 4) {
        s += partials[b * 256 + d];
        q += partials[b * 256 + 128 + d];
    }
    ls[threadIdx.x] = s; lq[threadIdx.x] = q;
    __syncthreads();
    if (threadIdx.x < 128) {
        s = ls[d] + ls[128 + d] + ls[256 + d] + ls[384 + d];
        q = lq[d] + lq[128 + d] + lq[256 + d] + lq[384 + d];
        float mean = s * (1.f / N_NODES);
        float var  = q * (1.f / N_NODES) - mean * mean;
        float a = gamma[d] * rsqrtf(var + BN_EPS);
        ac[d] = a;
        ac[DIM + d] = fmaf(-mean, a, beta[d]);
    }
}

// ---------------- Pool (applies last BN affine) ----------------
__global__ __launch_bounds__(128) void k_pool(const float* __restrict__ h, const float* __restrict__ ac,
                                              const int* __restrict__ goff, float* __restrict__ pooled) {
    int g = blockIdx.x, d = threadIdx.x;
    int r0 = goff[g], r1 = goff[g + 1];
    float s = 0.f;
    for (int r = r0; r < r1; ++r) s += h[(long)r * DIM + d];
    int n = r1 - r0;
    float a = ac[d], c = ac[DIM + d];
    float denom = (float)(n > 0 ? n : 1);
    pooled[g * DIM + d] = (a * s + c * (float)n) / denom;
}

// ---------------- Final MLP ----------------
__global__ __launch_bounds__(64) void k_mlp(const float* __restrict__ pooled, const float* __restrict__ w1,
                                            const float* __restrict__ b1, const float* __restrict__ w2,
                                            const float* __restrict__ b2, float* __restrict__ out) {
    int g = blockIdx.x, j = threadIdx.x;
    const float* p = pooled + g * DIM;
    float h = b1[j];
#pragma unroll
    for (int k = 0; k < DIM; ++k) h = fmaf(p[k], w1[k * 64 + j], h);
    h = fmaxf(h, 0.f);
    float v = h * w2[j];
#pragma unroll
    for (int o = 32; o > 0; o >>= 1) v += __shfl_down(v, o);
    if (j == 0) out[g] = v + b2[0];
}

extern "C" void kernel_launch(void* const* d_in, const int* in_sizes, int n_in,
                              void* d_out, int out_size, void* d_ws, size_t ws_size,
                              hipStream_t stream) {
    const float* x      = (const float*)d_in[0];
    const int*   ei     = (const int*)d_in[1];
    const int*   batch  = (const int*)d_in[2];
    const float* Ws     = (const float*)d_in[3];
    const float* bs     = (const float*)d_in[4];
    const float* gammas = (const float*)d_in[5];
    const float* betas  = (const float*)d_in[6];
    const float* w1     = (const float*)d_in[7];
    const float* b1     = (const float*)d_in[8];
    const float* w2     = (const float*)d_in[9];
    const float* b2     = (const float*)d_in[10];
    float* out = (float*)d_out;

    char* p = (char*)d_ws;
    auto alloc = [&](size_t bytes) { void* r = (void*)p; p += (bytes + 255) & ~(size_t)255; return r; };
    int*   cnt    = (int*)alloc((size_t)N_NODES * 4);
    int*   gcnt   = (int*)alloc((size_t)N_GRAPHS * 4);
    int*   off    = (int*)alloc((size_t)(N_NODES + 1) * 4);
    int*   pos    = (int*)alloc((size_t)N_NODES * 4);
    int*   goff   = (int*)alloc((size_t)(N_GRAPHS + 1) * 4);
    int*   elist  = (int*)alloc((size_t)N_EDGES * 4);
    float* coef   = (float*)alloc((size_t)N_EDGES * 4);
    float* dinv   = (float*)alloc((size_t)N_NODES * 4);
    float* hA     = (float*)alloc((size_t)N_NODES * DIM * 4);
    float* hB     = (float*)alloc((size_t)N_NODES * DIM * 4);
    float* parts  = (float*)alloc((size_t)AGG_BLOCKS * 256 * 4);
    float* ac     = (float*)alloc(256 * 4);
    float* pooled = (float*)alloc((size_t)N_GRAPHS * DIM * 4);

    hipMemsetAsync(cnt, 0, (size_t)N_NODES * 4, stream);
    hipMemsetAsync(gcnt, 0, (size_t)N_GRAPHS * 4, stream);

    k_count_edges<<<(N_EDGES + 255) / 256, 256, 0, stream>>>(ei, cnt);
    k_count_nodes<<<(N_NODES + 255) / 256, 256, 0, stream>>>(batch, gcnt);
    k_scan<<<1, 1024, 0, stream>>>(cnt, off, pos, dinv, gcnt, goff);
    k_fill<<<(N_EDGES + 255) / 256, 256, 0, stream>>>(ei, pos, elist, coef, dinv);

    const float* cur_in = x;
    const float* cur_ac = nullptr;
    for (int l = 0; l < 3; ++l) {
        k_gemm<<<N_NODES / 64, 256, 0, stream>>>(cur_in, Ws + (size_t)l * DIM * DIM, bs + (size_t)l * DIM, cur_ac, hA);
        k_agg<<<AGG_BLOCKS, 256, 0, stream>>>(hA, off, elist, coef, dinv, hB, parts);
        k_stats<<<1, 512, 0, stream>>>(parts, gammas + (size_t)l * DIM, betas + (size_t)l * DIM, ac);
        cur_in = hB;
        cur_ac = ac;
    }
    k_pool<<<N_GRAPHS, 128, 0, stream>>>(hB, ac, goff, pooled);
    k_mlp<<<N_GRAPHS, 64, 0, stream>>>(pooled, w1, b1, w2, b2, out);
}

// Round 2
// 838.721 us; speedup vs baseline: 1.2615x; 1.2615x over previous
//
#include <hip/hip_runtime.h>

#define N_NODES 40000
#define N_EDGES 640000
#define DIM 128
#define N_GRAPHS 64
#define BN_EPS 1e-5f
#define AGG_BLOCKS 2048

// ---------------- CSR build ----------------
__global__ __launch_bounds__(256) void k_count_edges(const int* __restrict__ ei, int* __restrict__ cnt) {
    int e = blockIdx.x * 256 + threadIdx.x;
    if (e < N_EDGES) atomicAdd(&cnt[ei[N_EDGES + e]], 1);   // dst row
}

// batch is sorted: graph offsets are boundaries (no atomics).
__global__ __launch_bounds__(256) void k_boundaries(const int* __restrict__ batch, int* __restrict__ goff) {
    int n = blockIdx.x * 256 + threadIdx.x;
    if (n >= N_NODES) return;
    int b = batch[n];
    int bp = (n == 0) ? -1 : batch[n - 1];
    for (int g = bp + 1; g <= b; ++g) goff[g] = n;          // rare divergence
    if (n == N_NODES - 1)
        for (int g = b + 1; g <= N_GRAPHS; ++g) goff[g] = N_NODES;
}

__global__ __launch_bounds__(1024) void k_scan(const int* __restrict__ cnt, int* __restrict__ off,
                                               int* __restrict__ pos, float* __restrict__ dinv) {
    __shared__ int sums[1024];
    int t = threadIdx.x;
    const int CH = (N_NODES + 1023) / 1024;           // 40
    int b0 = t * CH;
    int b1 = b0 + CH; if (b1 > N_NODES) b1 = N_NODES;
    if (b0 > N_NODES) b0 = N_NODES;
    int s = 0;
    for (int i = b0; i < b1; ++i) s += cnt[i];
    sums[t] = s;
    __syncthreads();
    for (int d = 1; d < 1024; d <<= 1) {
        int v = (t >= d) ? sums[t - d] : 0;
        __syncthreads();
        sums[t] += v;
        __syncthreads();
    }
    int run = sums[t] - s;                            // exclusive prefix
    for (int i = b0; i < b1; ++i) {
        off[i] = run; pos[i] = run;
        dinv[i] = rsqrtf((float)(cnt[i] + 1));        // +1 self loop, always > 0
        run += cnt[i];
    }
    if (b1 == N_NODES && b0 < N_NODES) off[N_NODES] = run;
}

__global__ __launch_bounds__(256) void k_fill(const int* __restrict__ ei, int* __restrict__ pos,
                                              int* __restrict__ elist, float* __restrict__ coef,
                                              const float* __restrict__ dinv) {
    int e = blockIdx.x * 256 + threadIdx.x;
    if (e < N_EDGES) {
        int s = ei[e];                 // src row
        int d = ei[N_EDGES + e];       // dst row
        int p = atomicAdd(&pos[d], 1);
        elist[p] = s;
        coef[p]  = dinv[s] * dinv[d];
    }
}

// ---------------- GEMM: out = affine(in) @ W + b ----------------
__global__ __launch_bounds__(256) void k_gemm(const float* __restrict__ in, const float* __restrict__ W,
                                              const float* __restrict__ bias, const float* __restrict__ ac,
                                              float* __restrict__ out) {
    __shared__ float Wl[DIM * DIM];        // 64 KB
    __shared__ float inl[64 * 132];        // padded stride (conflict-free reads)
    int t = threadIdx.x;
    long row0 = (long)blockIdx.x * 64;

    const float4* W4 = (const float4*)W;
    float4* Wl4 = (float4*)Wl;
#pragma unroll
    for (int i = 0; i < 16; ++i) Wl4[t + i * 256] = W4[t + i * 256];

    for (int i = t; i < 2048; i += 256) {      // 64 rows x 32 float4
        int r = i >> 5, k4 = i & 31;
        float4 v = ((const float4*)(in + (row0 + r) * DIM))[k4];
        if (ac) {
            int k = k4 * 4;
            v.x = fmaf(ac[k + 0], v.x, ac[DIM + k + 0]);
            v.y = fmaf(ac[k + 1], v.y, ac[DIM + k + 1]);
            v.z = fmaf(ac[k + 2], v.z, ac[DIM + k + 2]);
            v.w = fmaf(ac[k + 3], v.w, ac[DIM + k + 3]);
        }
        *(float4*)&inl[r * 132 + k4 * 4] = v;
    }
    __syncthreads();

    int ty = t >> 4, tx = t & 15;
    int r0 = ty * 4, c0 = tx * 4;
    float acc[4][8];
#pragma unroll
    for (int i = 0; i < 4; ++i)
#pragma unroll
        for (int j = 0; j < 8; ++j) acc[i][j] = 0.f;

#pragma unroll 4
    for (int k = 0; k < DIM; ++k) {
        float av[4];
#pragma unroll
        for (int i = 0; i < 4; ++i) av[i] = inl[(r0 + i) * 132 + k];
        float4 wA = *(const float4*)&Wl[k * DIM + c0];
        float4 wB = *(const float4*)&Wl[k * DIM + 64 + c0];
        float wv[8] = {wA.x, wA.y, wA.z, wA.w, wB.x, wB.y, wB.z, wB.w};
#pragma unroll
        for (int i = 0; i < 4; ++i)
#pragma unroll
            for (int j = 0; j < 8; ++j)
                acc[i][j] = fmaf(av[i], wv[j], acc[i][j]);
    }

    float4 bA = *(const float4*)&bias[c0];
    float4 bB = *(const float4*)&bias[64 + c0];
#pragma unroll
    for (int i = 0; i < 4; ++i) {
        long r = row0 + r0 + i;
        float4 oA = make_float4(acc[i][0] + bA.x, acc[i][1] + bA.y, acc[i][2] + bA.z, acc[i][3] + bA.w);
        float4 oB = make_float4(acc[i][4] + bB.x, acc[i][5] + bB.y, acc[i][6] + bB.z, acc[i][7] + bB.w);
        *(float4*)&out[r * DIM + c0] = oA;
        *(float4*)&out[r * DIM + 64 + c0] = oB;
    }
}

// ---------------- Aggregation + ReLU + BN partial stats ----------------
__global__ __launch_bounds__(256) void k_agg(const float* __restrict__ hW, const int* __restrict__ off,
                                             const int* __restrict__ elist, const float* __restrict__ coef,
                                             const float* __restrict__ dinv, float* __restrict__ hout,
                                             float* __restrict__ partials) {
    __shared__ float colacc[256];
    colacc[threadIdx.x] = 0.f;
    __syncthreads();

    int lane = threadIdx.x & 63;
    int wid = (blockIdx.x * 256 + threadIdx.x) >> 6;
    const int NW = AGG_BLOCKS * 4;
    float s0 = 0.f, s1 = 0.f, q0 = 0.f, q1 = 0.f;

    for (int i = wid; i < N_NODES; i += NW) {
        float di = dinv[i];
        const float* rowi = hW + (long)i * DIM;
        float selfc = di * di;
        float a0 = rowi[lane] * selfc;
        float a1 = rowi[lane + 64] * selfc;
        int e  = off[i];
        int e1 = off[i + 1];
#pragma unroll 2
        for (; e < e1; ++e) {
            int s  = elist[e];
            float c = coef[e];
            const float* rs = hW + (long)s * DIM;
            a0 = fmaf(rs[lane], c, a0);
            a1 = fmaf(rs[lane + 64], c, a1);
        }
        a0 = fmaxf(a0, 0.f);
        a1 = fmaxf(a1, 0.f);
        hout[(long)i * DIM + lane]      = a0;
        hout[(long)i * DIM + lane + 64] = a1;
        s0 += a0; s1 += a1; q0 += a0 * a0; q1 += a1 * a1;
    }

    atomicAdd(&colacc[lane], s0);
    atomicAdd(&colacc[lane + 64], s1);
    atomicAdd(&colacc[lane + 128], q0);
    atomicAdd(&colacc[lane + 192], q1);
    __syncthreads();
    partials[(long)blockIdx.x * 256 + threadIdx.x] = colacc[threadIdx.x];
}

// ---------------- BN stats -> affine a,c ----------------
__global__ __launch_bounds__(1024) void k_stats(const float* __restrict__ partials,
                                                const float* __restrict__ gamma, const float* __restrict__ beta,
                                                float* __restrict__ ac) {
    __shared__ float ls[1024], lq[1024];
    int d = threadIdx.x & 127;
    int seg = threadIdx.x >> 7;                    // 8 segments
    float s = 0.f, q = 0.f;
    for (int b = seg; b < AGG_BLOCKS; b += 8) {
        s += partials[b * 256 + d];
        q += partials[b * 256 + 128 + d];
    }
    ls[threadIdx.x] = s; lq[threadIdx.x] = q;
    __syncthreads();
    if (threadIdx.x < 128) {
        s = 0.f; q = 0.f;
#pragma unroll
        for (int k = 0; k < 8; ++k) { s += ls[k * 128 + d]; q += lq[k * 128 + d]; }
        float mean = s * (1.f / N_NODES);
        float var  = q * (1.f / N_NODES) - mean * mean;
        float a = gamma[d] * rsqrtf(var + BN_EPS);
        ac[d] = a;
        ac[DIM + d] = fmaf(-mean, a, beta[d]);
    }
}

// ---------------- Pool (applies last BN affine) ----------------
__global__ __launch_bounds__(128) void k_pool(const float* __restrict__ h, const float* __restrict__ ac,
                                              const int* __restrict__ goff, float* __restrict__ pooled) {
    int g = blockIdx.x, d = threadIdx.x;
    int r0 = goff[g], r1 = goff[g + 1];
    float s = 0.f;
    for (int r = r0; r < r1; ++r) s += h[(long)r * DIM + d];
    int n = r1 - r0;
    float a = ac[d], c = ac[DIM + d];
    float denom = (float)(n > 0 ? n : 1);
    pooled[g * DIM + d] = (a * s + c * (float)n) / denom;
}

// ---------------- Final MLP ----------------
__global__ __launch_bounds__(64) void k_mlp(const float* __restrict__ pooled, const float* __restrict__ w1,
                                            const float* __restrict__ b1, const float* __restrict__ w2,
                                            const float* __restrict__ b2, float* __restrict__ out) {
    int g = blockIdx.x, j = threadIdx.x;
    const float* p = pooled + g * DIM;
    float h = b1[j];
#pragma unroll
    for (int k = 0; k < DIM; ++k) h = fmaf(p[k], w1[k * 64 + j], h);
    h = fmaxf(h, 0.f);
    float v = h * w2[j];
#pragma unroll
    for (int o = 32; o > 0; o >>= 1) v += __shfl_down(v, o);
    if (j == 0) out[g] = v + b2[0];
}

extern "C" void kernel_launch(void* const* d_in, const int* in_sizes, int n_in,
                              void* d_out, int out_size, void* d_ws, size_t ws_size,
                              hipStream_t stream) {
    const float* x      = (const float*)d_in[0];
    const int*   ei     = (const int*)d_in[1];
    const int*   batch  = (const int*)d_in[2];
    const float* Ws     = (const float*)d_in[3];
    const float* bs     = (const float*)d_in[4];
    const float* gammas = (const float*)d_in[5];
    const float* betas  = (const float*)d_in[6];
    const float* w1     = (const float*)d_in[7];
    const float* b1     = (const float*)d_in[8];
    const float* w2     = (const float*)d_in[9];
    const float* b2     = (const float*)d_in[10];
    float* out = (float*)d_out;

    char* p = (char*)d_ws;
    auto alloc = [&](size_t bytes) { void* r = (void*)p; p += (bytes + 255) & ~(size_t)255; return r; };
    int*   cnt    = (int*)alloc((size_t)N_NODES * 4);
    int*   off    = (int*)alloc((size_t)(N_NODES + 1) * 4);
    int*   pos    = (int*)alloc((size_t)N_NODES * 4);
    int*   goff   = (int*)alloc((size_t)(N_GRAPHS + 1) * 4);
    int*   elist  = (int*)alloc((size_t)N_EDGES * 4);
    float* coef   = (float*)alloc((size_t)N_EDGES * 4);
    float* dinv   = (float*)alloc((size_t)N_NODES * 4);
    float* hA     = (float*)alloc((size_t)N_NODES * DIM * 4);
    float* hB     = (float*)alloc((size_t)N_NODES * DIM * 4);
    float* parts  = (float*)alloc((size_t)AGG_BLOCKS * 256 * 4);
    float* ac     = (float*)alloc(256 * 4);
    float* pooled = (float*)alloc((size_t)N_GRAPHS * DIM * 4);

    hipMemsetAsync(cnt, 0, (size_t)N_NODES * 4, stream);

    k_count_edges<<<(N_EDGES + 255) / 256, 256, 0, stream>>>(ei, cnt);
    k_boundaries<<<(N_NODES + 255) / 256, 256, 0, stream>>>(batch, goff);
    k_scan<<<1, 1024, 0, stream>>>(cnt, off, pos, dinv);
    k_fill<<<(N_EDGES + 255) / 256, 256, 0, stream>>>(ei, pos, elist, coef, dinv);

    const float* cur_in = x;
    const float* cur_ac = nullptr;
    for (int l = 0; l < 3; ++l) {
        k_gemm<<<N_NODES / 64, 256, 0, stream>>>(cur_in, Ws + (size_t)l * DIM * DIM, bs + (size_t)l * DIM, cur_ac, hA);
        k_agg<<<AGG_BLOCKS, 256, 0, stream>>>(hA, off, elist, coef, dinv, hB, parts);
        k_stats<<<1, 1024, 0, stream>>>(parts, gammas + (size_t)l * DIM, betas + (size_t)l * DIM, ac);
        cur_in = hB;
        cur_ac = ac;
    }
    k_pool<<<N_GRAPHS, 128, 0, stream>>>(hB, ac, goff, pooled);
    k_mlp<<<N_GRAPHS, 64, 0, stream>>>(pooled, w1, b1, w2, b2, out);
}

// Round 3
// 511.982 us; speedup vs baseline: 2.0666x; 1.6382x over previous
//
#include <hip/hip_runtime.h>

#define N_NODES 40000
#define N_EDGES 640000
#define DIM 128
#define N_GRAPHS 64
#define BN_EPS 1e-5f
#define AGG_BLOCKS 2048

// ---------------- CSR build ----------------
__global__ __launch_bounds__(256) void k_count_edges(const int* __restrict__ ei, int* __restrict__ cnt) {
    int e = blockIdx.x * 256 + threadIdx.x;
    if (e < N_EDGES) atomicAdd(&cnt[ei[N_EDGES + e]], 1);   // dst row
}

// batch is sorted: graph offsets are boundaries (no atomics).
__global__ __launch_bounds__(256) void k_boundaries(const int* __restrict__ batch, int* __restrict__ goff) {
    int n = blockIdx.x * 256 + threadIdx.x;
    if (n >= N_NODES) return;
    int b = batch[n];
    int bp = (n == 0) ? -1 : batch[n - 1];
    for (int g = bp + 1; g <= b; ++g) goff[g] = n;          // rare divergence
    if (n == N_NODES - 1)
        for (int g = b + 1; g <= N_GRAPHS; ++g) goff[g] = N_NODES;
}

__global__ __launch_bounds__(1024) void k_scan(const int* __restrict__ cnt, int* __restrict__ off,
                                               int* __restrict__ pos, float* __restrict__ dinv) {
    __shared__ int sums[1024];
    int t = threadIdx.x;
    const int CH = (N_NODES + 1023) / 1024;           // 40
    int b0 = t * CH;
    int b1 = b0 + CH; if (b1 > N_NODES) b1 = N_NODES;
    if (b0 > N_NODES) b0 = N_NODES;
    int s = 0;
    for (int i = b0; i < b1; ++i) s += cnt[i];
    sums[t] = s;
    __syncthreads();
    for (int d = 1; d < 1024; d <<= 1) {
        int v = (t >= d) ? sums[t - d] : 0;
        __syncthreads();
        sums[t] += v;
        __syncthreads();
    }
    int run = sums[t] - s;                            // exclusive prefix
    for (int i = b0; i < b1; ++i) {
        off[i] = run; pos[i] = run;
        dinv[i] = rsqrtf((float)(cnt[i] + 1));        // +1 self loop, always > 0
        run += cnt[i];
    }
    if (b1 == N_NODES && b0 < N_NODES) off[N_NODES] = run;
}

__global__ __launch_bounds__(256) void k_fill(const int* __restrict__ ei, int* __restrict__ pos,
                                              int* __restrict__ elist, float* __restrict__ coef,
                                              const float* __restrict__ dinv) {
    int e = blockIdx.x * 256 + threadIdx.x;
    if (e < N_EDGES) {
        int s = ei[e];                 // src row
        int d = ei[N_EDGES + e];       // dst row
        int p = atomicAdd(&pos[d], 1);
        elist[p] = s;
        coef[p]  = dinv[s] * dinv[d];
    }
}

// ---------------- GEMM: out = affine(in) @ W + b ----------------
__global__ __launch_bounds__(256) void k_gemm(const float* __restrict__ in, const float* __restrict__ W,
                                              const float* __restrict__ bias, const float* __restrict__ ac,
                                              float* __restrict__ out) {
    __shared__ float Wl[DIM * DIM];        // 64 KB
    __shared__ float inl[64 * 132];        // padded stride (conflict-free reads)
    int t = threadIdx.x;
    long row0 = (long)blockIdx.x * 64;

    const float4* W4 = (const float4*)W;
    float4* Wl4 = (float4*)Wl;
#pragma unroll
    for (int i = 0; i < 16; ++i) Wl4[t + i * 256] = W4[t + i * 256];

    for (int i = t; i < 2048; i += 256) {      // 64 rows x 32 float4
        int r = i >> 5, k4 = i & 31;
        float4 v = ((const float4*)(in + (row0 + r) * DIM))[k4];
        if (ac) {
            int k = k4 * 4;
            v.x = fmaf(ac[k + 0], v.x, ac[DIM + k + 0]);
            v.y = fmaf(ac[k + 1], v.y, ac[DIM + k + 1]);
            v.z = fmaf(ac[k + 2], v.z, ac[DIM + k + 2]);
            v.w = fmaf(ac[k + 3], v.w, ac[DIM + k + 3]);
        }
        *(float4*)&inl[r * 132 + k4 * 4] = v;
    }
    __syncthreads();

    int ty = t >> 4, tx = t & 15;
    int r0 = ty * 4, c0 = tx * 4;
    float acc[4][8];
#pragma unroll
    for (int i = 0; i < 4; ++i)
#pragma unroll
        for (int j = 0; j < 8; ++j) acc[i][j] = 0.f;

#pragma unroll 4
    for (int k = 0; k < DIM; ++k) {
        float av[4];
#pragma unroll
        for (int i = 0; i < 4; ++i) av[i] = inl[(r0 + i) * 132 + k];
        float4 wA = *(const float4*)&Wl[k * DIM + c0];
        float4 wB = *(const float4*)&Wl[k * DIM + 64 + c0];
        float wv[8] = {wA.x, wA.y, wA.z, wA.w, wB.x, wB.y, wB.z, wB.w};
#pragma unroll
        for (int i = 0; i < 4; ++i)
#pragma unroll
            for (int j = 0; j < 8; ++j)
                acc[i][j] = fmaf(av[i], wv[j], acc[i][j]);
    }

    float4 bA = *(const float4*)&bias[c0];
    float4 bB = *(const float4*)&bias[64 + c0];
#pragma unroll
    for (int i = 0; i < 4; ++i) {
        long r = row0 + r0 + i;
        float4 oA = make_float4(acc[i][0] + bA.x, acc[i][1] + bA.y, acc[i][2] + bA.z, acc[i][3] + bA.w);
        float4 oB = make_float4(acc[i][4] + bB.x, acc[i][5] + bB.y, acc[i][6] + bB.z, acc[i][7] + bB.w);
        *(float4*)&out[r * DIM + c0] = oA;
        *(float4*)&out[r * DIM + 64 + c0] = oB;
    }
}

// ---------------- Aggregation + ReLU + BN partial stats ----------------
__global__ __launch_bounds__(256) void k_agg(const float* __restrict__ hW, const int* __restrict__ off,
                                             const int* __restrict__ elist, const float* __restrict__ coef,
                                             const float* __restrict__ dinv, float* __restrict__ hout,
                                             float* __restrict__ partials) {
    __shared__ float colacc[256];
    colacc[threadIdx.x] = 0.f;
    __syncthreads();

    int lane = threadIdx.x & 63;
    int wid = (blockIdx.x * 256 + threadIdx.x) >> 6;
    const int NW = AGG_BLOCKS * 4;
    float s0 = 0.f, s1 = 0.f, q0 = 0.f, q1 = 0.f;

    for (int i = wid; i < N_NODES; i += NW) {
        float di = dinv[i];
        const float* rowi = hW + (long)i * DIM;
        float selfc = di * di;
        float a0 = rowi[lane] * selfc;
        float a1 = rowi[lane + 64] * selfc;
        int e  = off[i];
        int e1 = off[i + 1];
#pragma unroll 2
        for (; e < e1; ++e) {
            int s  = elist[e];
            float c = coef[e];
            const float* rs = hW + (long)s * DIM;
            a0 = fmaf(rs[lane], c, a0);
            a1 = fmaf(rs[lane + 64], c, a1);
        }
        a0 = fmaxf(a0, 0.f);
        a1 = fmaxf(a1, 0.f);
        hout[(long)i * DIM + lane]      = a0;
        hout[(long)i * DIM + lane + 64] = a1;
        s0 += a0; s1 += a1; q0 += a0 * a0; q1 += a1 * a1;
    }

    atomicAdd(&colacc[lane], s0);
    atomicAdd(&colacc[lane + 64], s1);
    atomicAdd(&colacc[lane + 128], q0);
    atomicAdd(&colacc[lane + 192], q1);
    __syncthreads();
    partials[(long)blockIdx.x * 256 + threadIdx.x] = colacc[threadIdx.x];
}

// ---------------- BN stats -> affine a,c (8 blocks x 16 cols) ----------------
__global__ __launch_bounds__(1024) void k_stats(const float* __restrict__ partials,
                                                const float* __restrict__ gamma, const float* __restrict__ beta,
                                                float* __restrict__ ac) {
    __shared__ float ls[1024], lq[1024];
    int dd = threadIdx.x & 15;
    int seg = threadIdx.x >> 4;                    // 64 segments
    int d = blockIdx.x * 16 + dd;
    float s = 0.f, q = 0.f;
    for (int b = seg; b < AGG_BLOCKS; b += 64) {
        s += partials[b * 256 + d];
        q += partials[b * 256 + 128 + d];
    }
    ls[threadIdx.x] = s; lq[threadIdx.x] = q;
    __syncthreads();
    for (int off = 512; off >= 16; off >>= 1) {
        if (threadIdx.x < off) {
            ls[threadIdx.x] += ls[threadIdx.x + off];
            lq[threadIdx.x] += lq[threadIdx.x + off];
        }
        __syncthreads();
    }
    if (threadIdx.x < 16) {
        s = ls[threadIdx.x]; q = lq[threadIdx.x];
        float mean = s * (1.f / N_NODES);
        float var  = q * (1.f / N_NODES) - mean * mean;
        float a = gamma[d] * rsqrtf(var + BN_EPS);
        ac[d] = a;
        ac[DIM + d] = fmaf(-mean, a, beta[d]);
    }
}

// ---------------- Pool (applies last BN affine); 8 row-segments/block ----------------
__global__ __launch_bounds__(1024) void k_pool(const float* __restrict__ h, const float* __restrict__ ac,
                                               const int* __restrict__ goff, float* __restrict__ pooled) {
    __shared__ float red[1024];
    int g = blockIdx.x;
    int d = threadIdx.x & 127;
    int seg = threadIdx.x >> 7;                    // 8 segments
    int r0 = goff[g], r1 = goff[g + 1];
    float s = 0.f;
    for (int r = r0 + seg; r < r1; r += 8) s += h[(long)r * DIM + d];
    red[threadIdx.x] = s;
    __syncthreads();
    if (threadIdx.x < 512) red[threadIdx.x] += red[threadIdx.x + 512];
    __syncthreads();
    if (threadIdx.x < 256) red[threadIdx.x] += red[threadIdx.x + 256];
    __syncthreads();
    if (threadIdx.x < 128) {
        s = red[threadIdx.x] + red[threadIdx.x + 128];
        int n = r1 - r0;
        float a = ac[d], c = ac[DIM + d];
        float denom = (float)(n > 0 ? n : 1);
        pooled[g * DIM + d] = (a * s + c * (float)n) / denom;
    }
}

// ---------------- Final MLP ----------------
__global__ __launch_bounds__(64) void k_mlp(const float* __restrict__ pooled, const float* __restrict__ w1,
                                            const float* __restrict__ b1, const float* __restrict__ w2,
                                            const float* __restrict__ b2, float* __restrict__ out) {
    int g = blockIdx.x, j = threadIdx.x;
    const float* p = pooled + g * DIM;
    float h = b1[j];
#pragma unroll
    for (int k = 0; k < DIM; ++k) h = fmaf(p[k], w1[k * 64 + j], h);
    h = fmaxf(h, 0.f);
    float v = h * w2[j];
#pragma unroll
    for (int o = 32; o > 0; o >>= 1) v += __shfl_down(v, o);
    if (j == 0) out[g] = v + b2[0];
}

extern "C" void kernel_launch(void* const* d_in, const int* in_sizes, int n_in,
                              void* d_out, int out_size, void* d_ws, size_t ws_size,
                              hipStream_t stream) {
    const float* x      = (const float*)d_in[0];
    const int*   ei     = (const int*)d_in[1];
    const int*   batch  = (const int*)d_in[2];
    const float* Ws     = (const float*)d_in[3];
    const float* bs     = (const float*)d_in[4];
    const float* gammas = (const float*)d_in[5];
    const float* betas  = (const float*)d_in[6];
    const float* w1     = (const float*)d_in[7];
    const float* b1     = (const float*)d_in[8];
    const float* w2     = (const float*)d_in[9];
    const float* b2     = (const float*)d_in[10];
    float* out = (float*)d_out;

    char* p = (char*)d_ws;
    auto alloc = [&](size_t bytes) { void* r = (void*)p; p += (bytes + 255) & ~(size_t)255; return r; };
    int*   cnt    = (int*)alloc((size_t)N_NODES * 4);
    int*   off    = (int*)alloc((size_t)(N_NODES + 1) * 4);
    int*   pos    = (int*)alloc((size_t)N_NODES * 4);
    int*   goff   = (int*)alloc((size_t)(N_GRAPHS + 1) * 4);
    int*   elist  = (int*)alloc((size_t)N_EDGES * 4);
    float* coef   = (float*)alloc((size_t)N_EDGES * 4);
    float* dinv   = (float*)alloc((size_t)N_NODES * 4);
    float* hA     = (float*)alloc((size_t)N_NODES * DIM * 4);
    float* hB     = (float*)alloc((size_t)N_NODES * DIM * 4);
    float* parts  = (float*)alloc((size_t)AGG_BLOCKS * 256 * 4);
    float* ac     = (float*)alloc(256 * 4);
    float* pooled = (float*)alloc((size_t)N_GRAPHS * DIM * 4);

    hipMemsetAsync(cnt, 0, (size_t)N_NODES * 4, stream);

    k_count_edges<<<(N_EDGES + 255) / 256, 256, 0, stream>>>(ei, cnt);
    k_boundaries<<<(N_NODES + 255) / 256, 256, 0, stream>>>(batch, goff);
    k_scan<<<1, 1024, 0, stream>>>(cnt, off, pos, dinv);
    k_fill<<<(N_EDGES + 255) / 256, 256, 0, stream>>>(ei, pos, elist, coef, dinv);

    const float* cur_in = x;
    const float* cur_ac = nullptr;
    for (int l = 0; l < 3; ++l) {
        k_gemm<<<N_NODES / 64, 256, 0, stream>>>(cur_in, Ws + (size_t)l * DIM * DIM, bs + (size_t)l * DIM, cur_ac, hA);
        k_agg<<<AGG_BLOCKS, 256, 0, stream>>>(hA, off, elist, coef, dinv, hB, parts);
        k_stats<<<8, 1024, 0, stream>>>(parts, gammas + (size_t)l * DIM, betas + (size_t)l * DIM, ac);
        cur_in = hB;
        cur_ac = ac;
    }
    k_pool<<<N_GRAPHS, 1024, 0, stream>>>(hB, ac, goff, pooled);
    k_mlp<<<N_GRAPHS, 64, 0, stream>>>(pooled, w1, b1, w2, b2, out);
}

// Round 4
// 407.158 us; speedup vs baseline: 2.5986x; 1.2575x over previous
//
#include <hip/hip_runtime.h>

#define N_NODES 40000
#define N_EDGES 640000
#define DIM 128
#define N_GRAPHS 64
#define BN_EPS 1e-5f
#define AGG_BLOCKS 2048
#define SCAN_NB 40   // ceil(40000/1024)

// ---------------- CSR build ----------------
__global__ __launch_bounds__(256) void k_count_edges(const int* __restrict__ ei, int* __restrict__ cnt) {
    int e = blockIdx.x * 256 + threadIdx.x;
    if (e < N_EDGES) atomicAdd(&cnt[ei[N_EDGES + e]], 1);   // dst row
}

// batch is sorted: graph offsets are boundaries (no atomics).
__global__ __launch_bounds__(256) void k_boundaries(const int* __restrict__ batch, int* __restrict__ goff) {
    int n = blockIdx.x * 256 + threadIdx.x;
    if (n >= N_NODES) return;
    int b = batch[n];
    int bp = (n == 0) ? -1 : batch[n - 1];
    for (int g = bp + 1; g <= b; ++g) goff[g] = n;          // rare divergence
    if (n == N_NODES - 1)
        for (int g = b + 1; g <= N_GRAPHS; ++g) goff[g] = N_NODES;
}

// ---- 3-pass parallel exclusive scan of cnt -> off, plus pos/dinv fill ----
__global__ __launch_bounds__(1024) void k_scan_blk(const int* __restrict__ cnt, int* __restrict__ off,
                                                   int* __restrict__ blocksum) {
    __shared__ int sums[1024];
    int i = blockIdx.x * 1024 + threadIdx.x;
    int v = (i < N_NODES) ? cnt[i] : 0;
    sums[threadIdx.x] = v;
    __syncthreads();
    for (int d = 1; d < 1024; d <<= 1) {
        int t = (threadIdx.x >= d) ? sums[threadIdx.x - d] : 0;
        __syncthreads();
        sums[threadIdx.x] += t;
        __syncthreads();
    }
    if (i < N_NODES) off[i] = sums[threadIdx.x] - v;        // exclusive within block
    if (threadIdx.x == 1023) blocksum[blockIdx.x] = sums[1023];
}

__global__ void k_scan_tops(const int* __restrict__ blocksum, int* __restrict__ blockoff) {
    if (threadIdx.x == 0) {
        int run = 0;
        for (int b = 0; b < SCAN_NB; ++b) { blockoff[b] = run; run += blocksum[b]; }
        blockoff[SCAN_NB] = run;
    }
}

__global__ __launch_bounds__(1024) void k_scan_fix(const int* __restrict__ cnt, const int* __restrict__ blockoff,
                                                   int* __restrict__ off, int* __restrict__ pos,
                                                   float* __restrict__ dinv) {
    int i = blockIdx.x * 1024 + threadIdx.x;
    if (i < N_NODES) {
        int o = off[i] + blockoff[blockIdx.x];
        off[i] = o; pos[i] = o;
        dinv[i] = rsqrtf((float)(cnt[i] + 1));              // +1 self loop, always > 0
    }
    if (i == 0) off[N_NODES] = blockoff[SCAN_NB];
}

__global__ __launch_bounds__(256) void k_fill(const int* __restrict__ ei, int* __restrict__ pos,
                                              int* __restrict__ elist, float* __restrict__ coef,
                                              const float* __restrict__ dinv) {
    int e = blockIdx.x * 256 + threadIdx.x;
    if (e < N_EDGES) {
        int s = ei[e];                 // src row
        int d = ei[N_EDGES + e];       // dst row
        int p = atomicAdd(&pos[d], 1);
        elist[p] = s;
        coef[p]  = dinv[s] * dinv[d];
    }
}

// ---------------- GEMM: out = affine(in) @ W + b ----------------
__global__ __launch_bounds__(256) void k_gemm(const float* __restrict__ in, const float* __restrict__ W,
                                              const float* __restrict__ bias, const float* __restrict__ ac,
                                              float* __restrict__ out) {
    __shared__ float Wl[DIM * DIM];        // 64 KB
    __shared__ float inl[64 * 132];        // padded stride (conflict-free reads)
    int t = threadIdx.x;
    long row0 = (long)blockIdx.x * 64;

    const float4* W4 = (const float4*)W;
    float4* Wl4 = (float4*)Wl;
#pragma unroll
    for (int i = 0; i < 16; ++i) Wl4[t + i * 256] = W4[t + i * 256];

    for (int i = t; i < 2048; i += 256) {      // 64 rows x 32 float4
        int r = i >> 5, k4 = i & 31;
        float4 v = ((const float4*)(in + (row0 + r) * DIM))[k4];
        if (ac) {
            int k = k4 * 4;
            v.x = fmaf(ac[k + 0], v.x, ac[DIM + k + 0]);
            v.y = fmaf(ac[k + 1], v.y, ac[DIM + k + 1]);
            v.z = fmaf(ac[k + 2], v.z, ac[DIM + k + 2]);
            v.w = fmaf(ac[k + 3], v.w, ac[DIM + k + 3]);
        }
        *(float4*)&inl[r * 132 + k4 * 4] = v;
    }
    __syncthreads();

    int ty = t >> 4, tx = t & 15;
    int r0 = ty * 4, c0 = tx * 4;
    float acc[4][8];
#pragma unroll
    for (int i = 0; i < 4; ++i)
#pragma unroll
        for (int j = 0; j < 8; ++j) acc[i][j] = 0.f;

#pragma unroll 4
    for (int k = 0; k < DIM; ++k) {
        float av[4];
#pragma unroll
        for (int i = 0; i < 4; ++i) av[i] = inl[(r0 + i) * 132 + k];
        float4 wA = *(const float4*)&Wl[k * DIM + c0];
        float4 wB = *(const float4*)&Wl[k * DIM + 64 + c0];
        float wv[8] = {wA.x, wA.y, wA.z, wA.w, wB.x, wB.y, wB.z, wB.w};
#pragma unroll
        for (int i = 0; i < 4; ++i)
#pragma unroll
            for (int j = 0; j < 8; ++j)
                acc[i][j] = fmaf(av[i], wv[j], acc[i][j]);
    }

    float4 bA = *(const float4*)&bias[c0];
    float4 bB = *(const float4*)&bias[64 + c0];
#pragma unroll
    for (int i = 0; i < 4; ++i) {
        long r = row0 + r0 + i;
        float4 oA = make_float4(acc[i][0] + bA.x, acc[i][1] + bA.y, acc[i][2] + bA.z, acc[i][3] + bA.w);
        float4 oB = make_float4(acc[i][4] + bB.x, acc[i][5] + bB.y, acc[i][6] + bB.z, acc[i][7] + bB.w);
        *(float4*)&out[r * DIM + c0] = oA;
        *(float4*)&out[r * DIM + 64 + c0] = oB;
    }
}

// ---------------- Aggregation + ReLU + BN partial stats ----------------
__global__ __launch_bounds__(256) void k_agg(const float* __restrict__ hW, const int* __restrict__ off,
                                             const int* __restrict__ elist, const float* __restrict__ coef,
                                             const float* __restrict__ dinv, float* __restrict__ hout,
                                             float* __restrict__ partials) {
    __shared__ float colacc[256];
    colacc[threadIdx.x] = 0.f;
    __syncthreads();

    int lane = threadIdx.x & 63;
    int wid = (blockIdx.x * 256 + threadIdx.x) >> 6;
    const int NW = AGG_BLOCKS * 4;
    float s0 = 0.f, s1 = 0.f, q0 = 0.f, q1 = 0.f;

    for (int i = wid; i < N_NODES; i += NW) {
        float di = dinv[i];
        const float* rowi = hW + (long)i * DIM;
        float selfc = di * di;
        float a0 = rowi[lane] * selfc;
        float a1 = rowi[lane + 64] * selfc;
        int e  = off[i];
        int e1 = off[i + 1];
#pragma unroll 2
        for (; e < e1; ++e) {
            int s  = elist[e];
            float c = coef[e];
            const float* rs = hW + (long)s * DIM;
            a0 = fmaf(rs[lane], c, a0);
            a1 = fmaf(rs[lane + 64], c, a1);
        }
        a0 = fmaxf(a0, 0.f);
        a1 = fmaxf(a1, 0.f);
        hout[(long)i * DIM + lane]      = a0;
        hout[(long)i * DIM + lane + 64] = a1;
        s0 += a0; s1 += a1; q0 += a0 * a0; q1 += a1 * a1;
    }

    atomicAdd(&colacc[lane], s0);
    atomicAdd(&colacc[lane + 64], s1);
    atomicAdd(&colacc[lane + 128], q0);
    atomicAdd(&colacc[lane + 192], q1);
    __syncthreads();
    partials[(long)blockIdx.x * 256 + threadIdx.x] = colacc[threadIdx.x];
}

// ---------------- BN stats -> affine a,c (8 blocks x 16 cols) ----------------
__global__ __launch_bounds__(1024) void k_stats(const float* __restrict__ partials,
                                                const float* __restrict__ gamma, const float* __restrict__ beta,
                                                float* __restrict__ ac) {
    __shared__ float ls[1024], lq[1024];
    int dd = threadIdx.x & 15;
    int seg = threadIdx.x >> 4;                    // 64 segments
    int d = blockIdx.x * 16 + dd;
    float s = 0.f, q = 0.f;
    for (int b = seg; b < AGG_BLOCKS; b += 64) {
        s += partials[b * 256 + d];
        q += partials[b * 256 + 128 + d];
    }
    ls[threadIdx.x] = s; lq[threadIdx.x] = q;
    __syncthreads();
    for (int off = 512; off >= 16; off >>= 1) {
        if (threadIdx.x < off) {
            ls[threadIdx.x] += ls[threadIdx.x + off];
            lq[threadIdx.x] += lq[threadIdx.x + off];
        }
        __syncthreads();
    }
    if (threadIdx.x < 16) {
        s = ls[threadIdx.x]; q = lq[threadIdx.x];
        float mean = s * (1.f / N_NODES);
        float var  = q * (1.f / N_NODES) - mean * mean;
        float a = gamma[d] * rsqrtf(var + BN_EPS);
        ac[d] = a;
        ac[DIM + d] = fmaf(-mean, a, beta[d]);
    }
}

// ---------------- Pool (applies last BN affine); 8 row-segments/block ----------------
__global__ __launch_bounds__(1024) void k_pool(const float* __restrict__ h, const float* __restrict__ ac,
                                               const int* __restrict__ goff, float* __restrict__ pooled) {
    __shared__ float red[1024];
    int g = blockIdx.x;
    int d = threadIdx.x & 127;
    int seg = threadIdx.x >> 7;                    // 8 segments
    int r0 = goff[g], r1 = goff[g + 1];
    float s = 0.f;
    for (int r = r0 + seg; r < r1; r += 8) s += h[(long)r * DIM + d];
    red[threadIdx.x] = s;
    __syncthreads();
    if (threadIdx.x < 512) red[threadIdx.x] += red[threadIdx.x + 512];
    __syncthreads();
    if (threadIdx.x < 256) red[threadIdx.x] += red[threadIdx.x + 256];
    __syncthreads();
    if (threadIdx.x < 128) {
        s = red[threadIdx.x] + red[threadIdx.x + 128];
        int n = r1 - r0;
        float a = ac[d], c = ac[DIM + d];
        float denom = (float)(n > 0 ? n : 1);
        pooled[g * DIM + d] = (a * s + c * (float)n) / denom;
    }
}

// ---------------- Final MLP ----------------
__global__ __launch_bounds__(64) void k_mlp(const float* __restrict__ pooled, const float* __restrict__ w1,
                                            const float* __restrict__ b1, const float* __restrict__ w2,
                                            const float* __restrict__ b2, float* __restrict__ out) {
    int g = blockIdx.x, j = threadIdx.x;
    const float* p = pooled + g * DIM;
    float h = b1[j];
#pragma unroll
    for (int k = 0; k < DIM; ++k) h = fmaf(p[k], w1[k * 64 + j], h);
    h = fmaxf(h, 0.f);
    float v = h * w2[j];
#pragma unroll
    for (int o = 32; o > 0; o >>= 1) v += __shfl_down(v, o);
    if (j == 0) out[g] = v + b2[0];
}

extern "C" void kernel_launch(void* const* d_in, const int* in_sizes, int n_in,
                              void* d_out, int out_size, void* d_ws, size_t ws_size,
                              hipStream_t stream) {
    const float* x      = (const float*)d_in[0];
    const int*   ei     = (const int*)d_in[1];
    const int*   batch  = (const int*)d_in[2];
    const float* Ws     = (const float*)d_in[3];
    const float* bs     = (const float*)d_in[4];
    const float* gammas = (const float*)d_in[5];
    const float* betas  = (const float*)d_in[6];
    const float* w1     = (const float*)d_in[7];
    const float* b1     = (const float*)d_in[8];
    const float* w2     = (const float*)d_in[9];
    const float* b2     = (const float*)d_in[10];
    float* out = (float*)d_out;

    char* p = (char*)d_ws;
    auto alloc = [&](size_t bytes) { void* r = (void*)p; p += (bytes + 255) & ~(size_t)255; return r; };
    int*   cnt      = (int*)alloc((size_t)N_NODES * 4);
    int*   off      = (int*)alloc((size_t)(N_NODES + 1) * 4);
    int*   pos      = (int*)alloc((size_t)N_NODES * 4);
    int*   goff     = (int*)alloc((size_t)(N_GRAPHS + 1) * 4);
    int*   blocksum = (int*)alloc((size_t)(SCAN_NB + 1) * 4);
    int*   blockoff = (int*)alloc((size_t)(SCAN_NB + 1) * 4);
    int*   elist    = (int*)alloc((size_t)N_EDGES * 4);
    float* coef     = (float*)alloc((size_t)N_EDGES * 4);
    float* dinv     = (float*)alloc((size_t)N_NODES * 4);
    float* hA       = (float*)alloc((size_t)N_NODES * DIM * 4);
    float* hB       = (float*)alloc((size_t)N_NODES * DIM * 4);
    float* parts    = (float*)alloc((size_t)AGG_BLOCKS * 256 * 4);
    float* ac       = (float*)alloc(256 * 4);
    float* pooled   = (float*)alloc((size_t)N_GRAPHS * DIM * 4);

    hipMemsetAsync(cnt, 0, (size_t)N_NODES * 4, stream);

    k_count_edges<<<(N_EDGES + 255) / 256, 256, 0, stream>>>(ei, cnt);
    k_boundaries<<<(N_NODES + 255) / 256, 256, 0, stream>>>(batch, goff);
    k_scan_blk<<<SCAN_NB, 1024, 0, stream>>>(cnt, off, blocksum);
    k_scan_tops<<<1, 64, 0, stream>>>(blocksum, blockoff);
    k_scan_fix<<<SCAN_NB, 1024, 0, stream>>>(cnt, blockoff, off, pos, dinv);
    k_fill<<<(N_EDGES + 255) / 256, 256, 0, stream>>>(ei, pos, elist, coef, dinv);

    const float* cur_in = x;
    const float* cur_ac = nullptr;
    for (int l = 0; l < 3; ++l) {
        k_gemm<<<N_NODES / 64, 256, 0, stream>>>(cur_in, Ws + (size_t)l * DIM * DIM, bs + (size_t)l * DIM, cur_ac, hA);
        k_agg<<<AGG_BLOCKS, 256, 0, stream>>>(hA, off, elist, coef, dinv, hB, parts);
        k_stats<<<8, 1024, 0, stream>>>(parts, gammas + (size_t)l * DIM, betas + (size_t)l * DIM, ac);
        cur_in = hB;
        cur_ac = ac;
    }
    k_pool<<<N_GRAPHS, 1024, 0, stream>>>(hB, ac, goff, pooled);
    k_mlp<<<N_GRAPHS, 64, 0, stream>>>(pooled, w1, b1, w2, b2, out);
}